// Round 12
// baseline (120.722 us; speedup 1.0000x reference)
//
#include <hip/hip_runtime.h>
#include <stdint.h>
#include <stddef.h>

// GraphCoarsenLayer: out = x@W_self + mean(x[nbr[:, :16]])@W_neigh
//                        + mean(x[nbr[:,16:]])@W_coarsen + (b_self+b_neigh+b_coarsen)
// R12 = R9 revert + agg-in-fp8. Gather (R9 sliced, L2-resident) now writes agg as
// fp8 chunks (halves its writes); GEMM A = [x bf16 g<32 | agg fp8 g 32..95] — A HBM
// read drops 77->52MB (GEMM was measured A-HBM-bound). fp8 agg error adds ~0.007
// sigma in quadrature -> predicted absmax ~0.045 (threshold 0.0728).

#define NN   50000
#define NPAD 50176          // multiple of 128; 392 row-tiles of 128
#define ODIM 256
#define NTK  24             // 768 / 32 K-steps

typedef __bf16 bf16x8 __attribute__((ext_vector_type(8)));
typedef float  f32x4  __attribute__((ext_vector_type(4)));
typedef float  f32x2  __attribute__((ext_vector_type(2)));
typedef unsigned short u16x8 __attribute__((ext_vector_type(8)));

static __device__ __forceinline__ unsigned short f2b(float f) {
    unsigned u = __builtin_bit_cast(unsigned, f);
    u += 0x7fffu + ((u >> 16) & 1u);          // round-to-nearest-even
    return (unsigned short)(u >> 16);
}

// ---------------- kernel 1: pack weights (K-chunked) + bias sum ----------------
// Wb layout: [g*256 + n]*8 + j  where k = g*8 + j  (g = 0..95)
__global__ void k_prep_w(const float* __restrict__ Wself, const float* __restrict__ bself,
                         const float* __restrict__ Wneigh, const float* __restrict__ bneigh,
                         const float* __restrict__ Wcoar, const float* __restrict__ bcoar,
                         unsigned short* __restrict__ Wb, float* __restrict__ bias) {
    int k = blockIdx.x;      // 0..767
    int n = threadIdx.x;     // 0..255
    const float* W = (k < 256) ? Wself : (k < 512) ? Wneigh : Wcoar;
    int kl = k & 255;
    float v = W[(size_t)kl * ODIM + n];
    int g = k >> 3;
    int j = k & 7;
    Wb[((size_t)g * ODIM + n) * 8 + j] = f2b(v);
    if (k == 0) bias[n] = bself[n] + bneigh[n] + bcoar[n];
}

// ---------------- kernel 2: x (f32) -> Ax chunked g<32 (bf16) + X8s fp8 sliced --
__global__ void k_convert_x(const float* __restrict__ x, unsigned short* __restrict__ Ax,
                            unsigned char* __restrict__ X8s) {
    int p = blockIdx.x * 256 + threadIdx.x;    // one 8-element chunk per thread
    if (p >= NN * 32) return;
    int i  = p >> 5;
    int c8 = p & 31;
    const f32x4* src = (const f32x4*)(x + (size_t)i * 256 + c8 * 8);
    f32x4 v0 = src[0], v1 = src[1];
    u16x8 o;
    o[0] = f2b(v0[0]); o[1] = f2b(v0[1]); o[2] = f2b(v0[2]); o[3] = f2b(v0[3]);
    o[4] = f2b(v1[0]); o[5] = f2b(v1[1]); o[6] = f2b(v1[2]); o[7] = f2b(v1[3]);
    *(u16x8*)(Ax + ((size_t)c8 * NPAD + i) * 8) = o;      // chunked bf16 layout
    unsigned d0 = __builtin_amdgcn_cvt_pk_fp8_f32(v0[0], v0[1], 0, false);
    d0 = (unsigned)__builtin_amdgcn_cvt_pk_fp8_f32(v0[2], v0[3], d0, true);
    unsigned d1 = __builtin_amdgcn_cvt_pk_fp8_f32(v1[0], v1[1], 0, false);
    d1 = (unsigned)__builtin_amdgcn_cvt_pk_fp8_f32(v1[2], v1[3], d1, true);
    uint2 o8; o8.x = d0; o8.y = d1;
    const int s = c8 >> 3, b = c8 & 7;         // column slice 0..3, 8B sub-chunk
    *(uint2*)(X8s + ((size_t)s * NN + i) * 64 + b * 8) = o8;
}

// ---------------- kernel 3: sliced gather-mean -> AGG8 fp8 chunks --------------
// Block = 16 nodes x 1 slice (64 cols), L2-resident 3.2MB slice table (R9 proven).
// Output now fp8 chunked [ga][row][8B]: sampled ga = s*8+c, unsampled ga = 32+s*8+c.
__global__ __launch_bounds__(256) void k_gather(const int* __restrict__ nbr,
                                                const unsigned char* __restrict__ X8s,
                                                unsigned char* __restrict__ AGG8) {
    __shared__ int nbl[512];                     // 16 nodes x 32 neighbor ids
    __shared__ unsigned char aggl8[16][136];     // [node][s 0..63 | u 64..127 | pad]
    const int tid   = threadIdx.x;
    const int node0 = blockIdx.x * 16;           // 3125 * 16 = 50000 exactly
    const int s     = blockIdx.y;                // slice 0..3
    nbl[tid]       = nbr[(size_t)node0 * 32 + tid];
    nbl[tid + 256] = nbr[(size_t)node0 * 32 + 256 + tid];
    __syncthreads();

    const int wid = tid >> 6, lane = tid & 63;
    const int nl  = wid * 4 + (lane >> 4);       // local node 0..15
    const int col = lane & 15;                   // 4B column group in slice
    const unsigned char* base = X8s + (size_t)s * NN * 64 + col * 4;
    float s0 = 0, s1 = 0, s2 = 0, s3 = 0, u0 = 0, u1 = 0, u2 = 0, u3 = 0;
#pragma unroll
    for (int j = 0; j < 32; ++j) {
        const int idx = nbl[nl * 32 + j];
        unsigned d = *(const unsigned*)(base + (size_t)idx * 64);
        f32x2 lo = __builtin_amdgcn_cvt_pk_f32_fp8(d, false);
        f32x2 hi = __builtin_amdgcn_cvt_pk_f32_fp8(d, true);
        if (j < 16) { s0 += lo[0]; s1 += lo[1]; s2 += hi[0]; s3 += hi[1]; }
        else        { u0 += lo[0]; u1 += lo[1]; u2 += hi[0]; u3 += hi[1]; }
    }
    const float rc = 1.0f / 16.0f;
    unsigned ws_ = __builtin_amdgcn_cvt_pk_fp8_f32(s0 * rc, s1 * rc, 0, false);
    ws_ = (unsigned)__builtin_amdgcn_cvt_pk_fp8_f32(s2 * rc, s3 * rc, ws_, true);
    unsigned wu_ = __builtin_amdgcn_cvt_pk_fp8_f32(u0 * rc, u1 * rc, 0, false);
    wu_ = (unsigned)__builtin_amdgcn_cvt_pk_fp8_f32(u2 * rc, u3 * rc, wu_, true);
    *(unsigned*)&aggl8[nl][col * 4]      = ws_;
    *(unsigned*)&aggl8[nl][64 + col * 4] = wu_;
    __syncthreads();

    // write-out: thread tau -> (c = tau>>4, row = tau&15); 16 consecutive threads
    // write 16 consecutive node-rows of one chunk = 128B contiguous.
    const int c = tid >> 4, row = tid & 15;
    uint2 v = *(const uint2*)&aggl8[row][c * 8];
    const int ga = (c < 8) ? (s * 8 + c) : (32 + s * 8 + (c - 8));
    *(uint2*)(AGG8 + ((size_t)ga * NPAD + node0 + row) * 8) = v;
}

// ---------------- kernel 4: GEMM  out[N,256] = A[N,768] @ Wb + bias ------------
// BM=128, BN=256 (A read once), BK=32. 512 threads = 8 waves (2x4), wave 64x64.
// A: t<8 bf16 chunks (Ax), t>=8 fp8 chunks (AGG8, width-16 gl_lds staged twice for
// uniform 3 loads/wave). 3-buffer LDS, counted vmcnt(3), ONE barrier per K-step.
__global__ __launch_bounds__(512, 4) void k_gemm(const unsigned short* __restrict__ Ax,
                                                 const unsigned char* __restrict__ AGG8,
                                                 const unsigned short* __restrict__ Wb,
                                                 const float* __restrict__ bias,
                                                 float* __restrict__ out) {
    __shared__ __align__(16) unsigned short lds[3][12288];  // [buf][A 8KB | B 16KB]
    const int tid  = threadIdx.x;
    const int wid  = tid >> 6;
    const int lane = tid & 63;
    const int l15 = lane & 15, l4 = lane >> 4;
    const int row0 = blockIdx.x * 128;
    const int wr = wid >> 2, wc = wid & 3;      // 2x4 wave grid, wave = 64m x 64n

    f32x4 acc[4][4] = {};

    auto stage = [&](int buf, int t) {
#pragma unroll
        for (int i = 0; i < 3; ++i) {
            const int u = wid * 3 + i;          // 0..23
            if (u < 8) {                        // A units
                if (t < 8) {                    // bf16: 8 x 1KB (kc, half)
                    const int kc = u >> 1, half = u & 1;
                    const int g  = t * 4 + kc;
                    const unsigned short* src =
                        Ax + ((size_t)g * NPAD + row0 + half * 64 + lane) * 8;
                    unsigned short* dst = &lds[buf][kc * 1024 + half * 512];
                    __builtin_amdgcn_global_load_lds(
                        (const __attribute__((address_space(1))) void*)src,
                        (__attribute__((address_space(3))) void*)dst, 16, 0, 0);
                } else {                        // fp8: 4 x 1KB chunks, each staged
                    const int kc = u >> 1;      // twice (idempotent) for uniformity
                    const int ga = t * 4 + kc - 32;
                    const unsigned char* src =
                        AGG8 + ((size_t)ga * NPAD + row0) * 8 + lane * 16;
                    unsigned short* dst = &lds[buf][kc * 512];
                    __builtin_amdgcn_global_load_lds(
                        (const __attribute__((address_space(1))) void*)src,
                        (__attribute__((address_space(3))) void*)dst, 16, 0, 0);
                }
            } else {                            // B units: 16 x 1KB
                const int v = u - 8;
                const int kc = v >> 2, nq = v & 3;
                const int g  = t * 4 + kc;
                const unsigned short* src =
                    Wb + ((size_t)g * ODIM + nq * 64 + lane) * 8;
                unsigned short* dst = &lds[buf][4096 + kc * 2048 + nq * 512];
                __builtin_amdgcn_global_load_lds(
                    (const __attribute__((address_space(1))) void*)src,
                    (__attribute__((address_space(3))) void*)dst, 16, 0, 0);
            }
        }
    };

    stage(0, 0);
    stage(1, 1);
#pragma unroll
    for (int t = 0; t < NTK; ++t) {
        if (t < NTK - 1) asm volatile("s_waitcnt vmcnt(3)" ::: "memory");
        else            asm volatile("s_waitcnt vmcnt(0)" ::: "memory");
        __builtin_amdgcn_s_barrier();           // all waves' tile-t loads visible
        __builtin_amdgcn_sched_barrier(0);
        if (t + 2 < NTK) stage((t + 2) % 3, t + 2);  // overwrites buf read at t-1
        const int buf = t % 3;
        bf16x8 af[4], bfr[4];
        if (t < 8) {
#pragma unroll
            for (int mi = 0; mi < 4; ++mi)
                af[mi] = *(const bf16x8*)&lds[buf][l4 * 1024 + (wr * 64 + mi * 16 + l15) * 8];
        } else {
#pragma unroll
            for (int mi = 0; mi < 4; ++mi) {
                uint2 d = *(const uint2*)&lds[buf][l4 * 512 + (wr * 64 + mi * 16 + l15) * 4];
                f32x2 a0 = __builtin_amdgcn_cvt_pk_f32_fp8(d.x, false);
                f32x2 a1 = __builtin_amdgcn_cvt_pk_f32_fp8(d.x, true);
                f32x2 a2 = __builtin_amdgcn_cvt_pk_f32_fp8(d.y, false);
                f32x2 a3 = __builtin_amdgcn_cvt_pk_f32_fp8(d.y, true);
                bf16x8 a;
                a[0] = (__bf16)a0[0]; a[1] = (__bf16)a0[1];
                a[2] = (__bf16)a1[0]; a[3] = (__bf16)a1[1];
                a[4] = (__bf16)a2[0]; a[5] = (__bf16)a2[1];
                a[6] = (__bf16)a3[0]; a[7] = (__bf16)a3[1];
                af[mi] = a;
            }
        }
#pragma unroll
        for (int ni = 0; ni < 4; ++ni)
            bfr[ni] = *(const bf16x8*)&lds[buf][4096 + l4 * 2048 + (wc * 64 + ni * 16 + l15) * 8];
#pragma unroll
        for (int mi = 0; mi < 4; ++mi)
#pragma unroll
            for (int ni = 0; ni < 4; ++ni)
                acc[mi][ni] = __builtin_amdgcn_mfma_f32_16x16x32_bf16(
                    af[mi], bfr[ni], acc[mi][ni], 0, 0, 0);
    }

    // epilogue: D layout col=lane&15, row=(lane>>4)*4+r
#pragma unroll
    for (int mi = 0; mi < 4; ++mi) {
        const int row = row0 + wr * 64 + mi * 16 + l4 * 4;
#pragma unroll
        for (int ni = 0; ni < 4; ++ni) {
            const int col = wc * 64 + ni * 16 + l15;
            const float bb = bias[col];
            f32x4 v = acc[mi][ni];
#pragma unroll
            for (int r = 0; r < 4; ++r) {
                const int rr = row + r;
                if (rr < NN) out[(size_t)rr * ODIM + col] = v[r] + bb;
            }
        }
    }
}

// ---------------- launch -------------------------------------------------------
extern "C" void kernel_launch(void* const* d_in, const int* in_sizes, int n_in,
                              void* d_out, int out_size, void* d_ws, size_t ws_size,
                              hipStream_t stream) {
    const float* x      = (const float*)d_in[0];
    const float* Wself  = (const float*)d_in[1];
    const float* bself  = (const float*)d_in[2];
    const float* Wneigh = (const float*)d_in[3];
    const float* bneigh = (const float*)d_in[4];
    const float* Wcoar  = (const float*)d_in[5];
    const float* bcoar  = (const float*)d_in[6];
    const int*   nbr    = (const int*)d_in[7];
    float* out = (float*)d_out;

    // workspace: Ax 25.7MB | X8s 12.8MB | AGG8 25.7MB | Wb 384KB | bias ~= 64.6MB
    unsigned short* Ax   = (unsigned short*)d_ws;                  // 32 x NPAD x 8 bf16
    unsigned char*  X8s  = (unsigned char*)(Ax + (size_t)32 * NPAD * 8);
    unsigned char*  AGG8 = X8s + (size_t)4 * NN * 64;              // 64 x NPAD x 8 fp8
    unsigned short* Wb   = (unsigned short*)(AGG8 + (size_t)64 * NPAD * 8);
    float*          bias = (float*)(Wb + (size_t)96 * ODIM * 8);

    k_prep_w<<<768, 256, 0, stream>>>(Wself, bself, Wneigh, bneigh, Wcoar, bcoar, Wb, bias);
    k_convert_x<<<(NN * 32 + 255) / 256, 256, 0, stream>>>(x, Ax, X8s);
    k_gather<<<dim3(3125, 4), 256, 0, stream>>>(nbr, X8s, AGG8);
    k_gemm<<<NPAD / 128, 512, 0, stream>>>(Ax, AGG8, Wb, bias, out);
}

// Round 13
// 98.555 us; speedup vs baseline: 1.2249x; 1.2249x over previous
//
#include <hip/hip_runtime.h>
#include <stdint.h>
#include <stddef.h>

// GraphCoarsenLayer: out = x@W_self + mean(x[nbr[:, :16]])@W_neigh
//                        + mean(x[nbr[:,16:]])@W_coarsen + (b_self+b_neigh+b_coarsen)
// R13 = exact revert to R9 (measured best: 98.1us). Pipeline:
//  prep_w:   pack Wb K-chunked [g][n][8] bf16 + bias sum           (~2us)
//  convert:  x -> Ax bf16 chunks g<32 + X8s fp8 column-sliced      (~13.5us, HBM floor)
//  gather:   column-sliced (4 x 3.2MB L2-resident tables), 16 nodes/block,
//            16 lanes/node -> agg bf16 chunks g 32..95              (~45.5us, random-row ceiling)
//  gemm:     BM=128 x BN=256 (A read once), BK=32, 8 waves 64x64,
//            3-buffer global_load_lds + counted vmcnt(3)            (~37us, best of 6 structures)

#define NN   50000
#define NPAD 50176          // multiple of 128; 392 row-tiles of 128
#define ODIM 256
#define NTK  24             // 768 / 32 K-steps

typedef __bf16 bf16x8 __attribute__((ext_vector_type(8)));
typedef float  f32x4  __attribute__((ext_vector_type(4)));
typedef float  f32x2  __attribute__((ext_vector_type(2)));
typedef unsigned short u16x8 __attribute__((ext_vector_type(8)));
typedef unsigned short u16x4 __attribute__((ext_vector_type(4)));

static __device__ __forceinline__ unsigned short f2b(float f) {
    unsigned u = __builtin_bit_cast(unsigned, f);
    u += 0x7fffu + ((u >> 16) & 1u);          // round-to-nearest-even
    return (unsigned short)(u >> 16);
}

// ---------------- kernel 1: pack weights (K-chunked) + bias sum ----------------
// Wb layout: [g*256 + n]*8 + j  where k = g*8 + j  (g = 0..95)
__global__ void k_prep_w(const float* __restrict__ Wself, const float* __restrict__ bself,
                         const float* __restrict__ Wneigh, const float* __restrict__ bneigh,
                         const float* __restrict__ Wcoar, const float* __restrict__ bcoar,
                         unsigned short* __restrict__ Wb, float* __restrict__ bias) {
    int k = blockIdx.x;      // 0..767
    int n = threadIdx.x;     // 0..255
    const float* W = (k < 256) ? Wself : (k < 512) ? Wneigh : Wcoar;
    int kl = k & 255;
    float v = W[(size_t)kl * ODIM + n];
    int g = k >> 3;
    int j = k & 7;
    Wb[((size_t)g * ODIM + n) * 8 + j] = f2b(v);
    if (k == 0) bias[n] = bself[n] + bneigh[n] + bcoar[n];
}

// ---------------- kernel 2: x (f32) -> Ax chunked g<32 (bf16) + X8s fp8 sliced --
__global__ void k_convert_x(const float* __restrict__ x, unsigned short* __restrict__ Ax,
                            unsigned char* __restrict__ X8s) {
    int p = blockIdx.x * 256 + threadIdx.x;    // one 8-element chunk per thread
    if (p >= NN * 32) return;
    int i  = p >> 5;
    int c8 = p & 31;
    const f32x4* src = (const f32x4*)(x + (size_t)i * 256 + c8 * 8);
    f32x4 v0 = src[0], v1 = src[1];
    u16x8 o;
    o[0] = f2b(v0[0]); o[1] = f2b(v0[1]); o[2] = f2b(v0[2]); o[3] = f2b(v0[3]);
    o[4] = f2b(v1[0]); o[5] = f2b(v1[1]); o[6] = f2b(v1[2]); o[7] = f2b(v1[3]);
    *(u16x8*)(Ax + ((size_t)c8 * NPAD + i) * 8) = o;      // chunked bf16 layout
    unsigned d0 = __builtin_amdgcn_cvt_pk_fp8_f32(v0[0], v0[1], 0, false);
    d0 = (unsigned)__builtin_amdgcn_cvt_pk_fp8_f32(v0[2], v0[3], d0, true);
    unsigned d1 = __builtin_amdgcn_cvt_pk_fp8_f32(v1[0], v1[1], 0, false);
    d1 = (unsigned)__builtin_amdgcn_cvt_pk_fp8_f32(v1[2], v1[3], d1, true);
    uint2 o8; o8.x = d0; o8.y = d1;
    const int s = c8 >> 3, b = c8 & 7;         // column slice 0..3, 8B sub-chunk
    *(uint2*)(X8s + ((size_t)s * NN + i) * 64 + b * 8) = o8;
}

// ---------------- kernel 3: sliced gather-mean -> Ax chunks g 32..95 -----------
// Block = 16 nodes x 1 slice (64 cols). 16 lanes per node, 4B/lane. Per-slice
// table (3.2MB) is L2-resident. Grid (3125, 4): slice on y -> time-windowed.
__global__ __launch_bounds__(256) void k_gather(const int* __restrict__ nbr,
                                                const unsigned char* __restrict__ X8s,
                                                unsigned short* __restrict__ Ax) {
    __shared__ int nbl[512];                     // 16 nodes x 32 neighbor ids
    __shared__ unsigned short aggl[16][136];     // [node][s 0..63 | u 64..127 | pad]
    const int tid   = threadIdx.x;
    const int node0 = blockIdx.x * 16;           // 3125 * 16 = 50000 exactly
    const int s     = blockIdx.y;                // slice 0..3
    nbl[tid]       = nbr[(size_t)node0 * 32 + tid];
    nbl[tid + 256] = nbr[(size_t)node0 * 32 + 256 + tid];
    __syncthreads();

    const int wid = tid >> 6, lane = tid & 63;
    const int nl  = wid * 4 + (lane >> 4);       // local node 0..15
    const int col = lane & 15;                   // 4B column group in slice
    const unsigned char* base = X8s + (size_t)s * NN * 64 + col * 4;
    float s0 = 0, s1 = 0, s2 = 0, s3 = 0, u0 = 0, u1 = 0, u2 = 0, u3 = 0;
#pragma unroll
    for (int j = 0; j < 32; ++j) {
        const int idx = nbl[nl * 32 + j];
        unsigned d = *(const unsigned*)(base + (size_t)idx * 64);
        f32x2 lo = __builtin_amdgcn_cvt_pk_f32_fp8(d, false);
        f32x2 hi = __builtin_amdgcn_cvt_pk_f32_fp8(d, true);
        if (j < 16) { s0 += lo[0]; s1 += lo[1]; s2 += hi[0]; s3 += hi[1]; }
        else        { u0 += lo[0]; u1 += lo[1]; u2 += hi[0]; u3 += hi[1]; }
    }
    const float rc = 1.0f / 16.0f;
    u16x4 os = { f2b(s0 * rc), f2b(s1 * rc), f2b(s2 * rc), f2b(s3 * rc) };
    u16x4 ou = { f2b(u0 * rc), f2b(u1 * rc), f2b(u2 * rc), f2b(u3 * rc) };
    *(u16x4*)&aggl[nl][col * 4]      = os;
    *(u16x4*)&aggl[nl][64 + col * 4] = ou;
    __syncthreads();

    // write-out: thread tau -> (gch = tau>>4, row = tau&15); 16 consecutive threads
    // write 16 consecutive rows of one g-chunk = 256B contiguous in Ax.
    const int gch = tid >> 4, row = tid & 15;
    u16x8 v = *(const u16x8*)&aggl[row][gch * 8];
    const int g = (gch < 8) ? (32 + s * 8 + gch) : (64 + s * 8 + (gch - 8));
    *(u16x8*)(Ax + ((size_t)g * NPAD + node0 + row) * 8) = v;
}

// ---------------- kernel 4: GEMM  out[N,256] = A[N,768] @ Wb + bias ------------
// BM=128, BN=256 (A read once), BK=32. 512 threads = 8 waves (2x4), wave 64x64.
// 3-buffer LDS, counted vmcnt(3), ONE barrier per K-step.
__global__ __launch_bounds__(512, 4) void k_gemm(const unsigned short* __restrict__ Ax,
                                                 const unsigned short* __restrict__ Wb,
                                                 const float* __restrict__ bias,
                                                 float* __restrict__ out) {
    __shared__ __align__(16) unsigned short lds[3][12288];  // [buf][A 4096 | B 8192] u16
    const int tid  = threadIdx.x;
    const int wid  = tid >> 6;
    const int lane = tid & 63;
    const int l15 = lane & 15, l4 = lane >> 4;
    const int row0 = blockIdx.x * 128;
    const int wr = wid >> 2, wc = wid & 3;      // 2x4 wave grid, wave = 64m x 64n

    f32x4 acc[4][4] = {};

    auto stage = [&](int buf, int t) {
#pragma unroll
        for (int i = 0; i < 3; ++i) {
            const int u = wid * 3 + i;          // 0..23
            if (u < 8) {
                const int kc = u >> 1, half = u & 1;
                const int g  = t * 4 + kc;
                const unsigned short* src =
                    Ax + ((size_t)g * NPAD + row0 + half * 64 + lane) * 8;
                unsigned short* dst = &lds[buf][kc * 1024 + half * 512];
                __builtin_amdgcn_global_load_lds(
                    (const __attribute__((address_space(1))) void*)src,
                    (__attribute__((address_space(3))) void*)dst, 16, 0, 0);
            } else {
                const int v = u - 8;
                const int kc = v >> 2, nq = v & 3;
                const int g  = t * 4 + kc;
                const unsigned short* src =
                    Wb + ((size_t)g * ODIM + nq * 64 + lane) * 8;
                unsigned short* dst = &lds[buf][4096 + kc * 2048 + nq * 512];
                __builtin_amdgcn_global_load_lds(
                    (const __attribute__((address_space(1))) void*)src,
                    (__attribute__((address_space(3))) void*)dst, 16, 0, 0);
            }
        }
    };

    stage(0, 0);
    stage(1, 1);
#pragma unroll
    for (int t = 0; t < NTK; ++t) {
        if (t < NTK - 1) asm volatile("s_waitcnt vmcnt(3)" ::: "memory");
        else            asm volatile("s_waitcnt vmcnt(0)" ::: "memory");
        __builtin_amdgcn_s_barrier();           // all waves' tile-t loads visible
        __builtin_amdgcn_sched_barrier(0);
        if (t + 2 < NTK) stage((t + 2) % 3, t + 2);  // overwrites buf read at t-1
        const int buf = t % 3;
        bf16x8 af[4], bfr[4];
#pragma unroll
        for (int mi = 0; mi < 4; ++mi)
            af[mi] = *(const bf16x8*)&lds[buf][l4 * 1024 + (wr * 64 + mi * 16 + l15) * 8];
#pragma unroll
        for (int ni = 0; ni < 4; ++ni)
            bfr[ni] = *(const bf16x8*)&lds[buf][4096 + l4 * 2048 + (wc * 64 + ni * 16 + l15) * 8];
#pragma unroll
        for (int mi = 0; mi < 4; ++mi)
#pragma unroll
            for (int ni = 0; ni < 4; ++ni)
                acc[mi][ni] = __builtin_amdgcn_mfma_f32_16x16x32_bf16(
                    af[mi], bfr[ni], acc[mi][ni], 0, 0, 0);
    }

    // epilogue: D layout col=lane&15, row=(lane>>4)*4+r
#pragma unroll
    for (int mi = 0; mi < 4; ++mi) {
        const int row = row0 + wr * 64 + mi * 16 + l4 * 4;
#pragma unroll
        for (int ni = 0; ni < 4; ++ni) {
            const int col = wc * 64 + ni * 16 + l15;
            const float bb = bias[col];
            f32x4 v = acc[mi][ni];
#pragma unroll
            for (int r = 0; r < 4; ++r) {
                const int rr = row + r;
                if (rr < NN) out[(size_t)rr * ODIM + col] = v[r] + bb;
            }
        }
    }
}

// ---------------- launch -------------------------------------------------------
extern "C" void kernel_launch(void* const* d_in, const int* in_sizes, int n_in,
                              void* d_out, int out_size, void* d_ws, size_t ws_size,
                              hipStream_t stream) {
    const float* x      = (const float*)d_in[0];
    const float* Wself  = (const float*)d_in[1];
    const float* bself  = (const float*)d_in[2];
    const float* Wneigh = (const float*)d_in[3];
    const float* bneigh = (const float*)d_in[4];
    const float* Wcoar  = (const float*)d_in[5];
    const float* bcoar  = (const float*)d_in[6];
    const int*   nbr    = (const int*)d_in[7];
    float* out = (float*)d_out;

    // workspace: Ax (77.1 MB, 96 chunks x NPAD x 8 bf16) | X8s (12.8) | Wb | bias ~= 90.3 MB
    unsigned short* Ax   = (unsigned short*)d_ws;
    unsigned char*  X8s  = (unsigned char*)(Ax + (size_t)96 * NPAD * 8);
    unsigned short* Wb   = (unsigned short*)(X8s + (size_t)4 * NN * 64);
    float*          bias = (float*)(Wb + (size_t)96 * ODIM * 8);

    k_prep_w<<<768, 256, 0, stream>>>(Wself, bself, Wneigh, bneigh, Wcoar, bcoar, Wb, bias);
    k_convert_x<<<(NN * 32 + 255) / 256, 256, 0, stream>>>(x, Ax, X8s);
    k_gather<<<dim3(3125, 4), 256, 0, stream>>>(nbr, X8s, Ax);
    k_gemm<<<NPAD / 128, 512, 0, stream>>>(Ax, Wb, bias, out);
}